// Round 9
// baseline (165.875 us; speedup 1.0000x reference)
//
#include <hip/hip_runtime.h>
#include <stdint.h>

#define S_LEN 2048
#define HDIM  64
#define NHEAD 32
#define NBATCH 4
// fold 1/sqrt(64) and log2(e) into Q so softmax uses exp2
#define QK_SCALE (0.125f * 1.44269504088896341f)
#define DEFER_THR 8.0f
#define NEG_BIG (-1e30f)

typedef float f32x16 __attribute__((ext_vector_type(16)));
typedef short bf16x8 __attribute__((ext_vector_type(8)));

// ---- workspace layout (bytes) ----
#define WS_MB   0                          // 4*32 u64 mask words (1 KiB)
#define WS_MVP  1024                       // meanV partials bf16 [32][16][64] (64 KiB)
#define WS_KBF  66560                      // K images, 8 MiB
#define IMGB    (NHEAD * 16 * 16384)
#define WS_VTBF (WS_KBF + (size_t)IMGB)    // V^T images, 8 MiB

static __device__ __forceinline__ unsigned int cvt_pk_bf16(float lo, float hi) {
    unsigned int r;
    asm("v_cvt_pk_bf16_f32 %0, %1, %2" : "=v"(r) : "v"(lo), "v"(hi));
    return r;  // low16 = bf16(lo), high16 = bf16(hi)
}
static __device__ __forceinline__ void permswap(unsigned int& a, unsigned int& b) {
    // after: a = concat(a[0:32], b[0:32]); b = concat(a_old[32:64], b[32:64])
    asm("v_permlane32_swap_b32 %0, %1" : "+v"(a), "+v"(b));
}
static __device__ __forceinline__ float bf2f(unsigned short u) {
    return __uint_as_float((unsigned int)u << 16);
}
static __device__ __forceinline__ void load_lds16(const void* g, void* l) {
    __builtin_amdgcn_global_load_lds(
        (const __attribute__((address_space(1))) uint32_t*)g,
        (__attribute__((address_space(3))) uint32_t*)l, 16, 0, 0);
}

// ---------- pre-kernel: K & V^T -> bf16 swizzled 128-key-tile images + meanV + masks ----------
// K image (16 KiB / tile): addr(key,d) = (key&63)*256 + (key>>6)*128 + ((d*2) ^ ((key&7)<<4))
//   NOTE: swizzle is (key&7)<<4 — bits 4..6 only, bijective within the key's 128-B half-row.
//   ((key&15)<<4 would set bit 7 = the half-selector -> row collisions; that was the r6 bug.)
// V^T image: addr(d,k) = d*256 + ((k*2) ^ ((d&15)<<4))  (256-B rows: 4-bit XOR is bijective)
__global__ __launch_bounds__(256) void cvt_kernel(
    const float* __restrict__ K, const float* __restrict__ V,
    const int* __restrict__ masks,
    uint8_t* __restrict__ Kbf, uint8_t* __restrict__ Vtbf,
    unsigned short* __restrict__ mvp, unsigned long long* __restrict__ MB)
{
    const int bid = blockIdx.x;
    const int bh  = (bid & 7) * 4 + ((bid >> 3) >> 4);  // XCD-matched to attn
    const int t   = (bid >> 3) & 15;                    // 128-key tile
    const int tid = threadIdx.x;
    const size_t ho  = (size_t)bh * S_LEN * HDIM;
    const size_t img = ((size_t)bh * 16 + t) * 16384;

    // ---- K image
    {
        const int kr = tid >> 1;            // local key 0..127
        const int dh = (tid & 1) * 32;      // d base 0/32
        const float4* kp = (const float4*)(K + ho + (size_t)(t * 128 + kr) * HDIM + dh);
        float4 a[8];
        #pragma unroll
        for (int i = 0; i < 8; ++i) a[i] = kp[i];
        const int rowb = (kr & 63) * 256 + (kr >> 6) * 128;
        const int swz  = (kr & 7) << 4;     // bijective within 128-B half-row
        #pragma unroll
        for (int ci = 0; ci < 4; ++ci) {
            int4 wv;
            wv.x = cvt_pk_bf16(a[2*ci].x,   a[2*ci].y);
            wv.y = cvt_pk_bf16(a[2*ci].z,   a[2*ci].w);
            wv.z = cvt_pk_bf16(a[2*ci+1].x, a[2*ci+1].y);
            wv.w = cvt_pk_bf16(a[2*ci+1].z, a[2*ci+1].w);
            *(int4*)&Kbf[img + rowb + ((dh * 2 + 16 * ci) ^ swz)] = wv;
        }
    }
    // ---- V^T image + meanV partial
    {
        const int d  = tid & 63;
        const int kg = tid >> 6;            // key group 0..3 (32 keys each)
        const float* vp = V + ho + (size_t)(t * 128 + kg * 32) * HDIM + d;
        float va[32];
        float psum = 0.f;
        #pragma unroll
        for (int i = 0; i < 32; ++i) { va[i] = vp[(size_t)i * HDIM]; psum += va[i]; }
        const int swz = (d & 15) << 4;
        #pragma unroll
        for (int ci = 0; ci < 4; ++ci) {
            int4 wv;
            wv.x = cvt_pk_bf16(va[8*ci+0], va[8*ci+1]);
            wv.y = cvt_pk_bf16(va[8*ci+2], va[8*ci+3]);
            wv.z = cvt_pk_bf16(va[8*ci+4], va[8*ci+5]);
            wv.w = cvt_pk_bf16(va[8*ci+6], va[8*ci+7]);
            *(int4*)&Vtbf[img + d * 256 + ((kg * 64 + 16 * ci) ^ swz)] = wv;
        }
        __shared__ float red[4][64];
        red[kg][d] = psum;
        __syncthreads();
        if (tid < 64) {
            float tot = red[0][tid] + red[1][tid] + red[2][tid] + red[3][tid];
            mvp[(bh * 16 + t) * 64 + tid] =
                (unsigned short)(cvt_pk_bf16(tot * (1.0f / (float)S_LEN), 0.f) & 0xFFFF);
        }
    }
    // ---- packed mask words (2 per 128-key tile), heads 0..3 only
    if (bh < NBATCH && tid < 128) {
        const int m = masks[bh * S_LEN + t * 128 + tid];
        const unsigned long long bits = __ballot(m != 0);
        if ((tid & 63) == 0) MB[bh * 32 + t * 2 + (tid >> 6)] = bits;
    }
}

// ---------- main flash-attention: QBLK=128, 4 waves x 32 q-rows, 32x32x16 MFMA ----------
// Dynamic LDS 65536: buf0 {K 16K @0, V 16K @16384}, buf1 @32768
__global__ __launch_bounds__(256, 2) void attn_fwd(
    const float* __restrict__ Q,
    const unsigned short* __restrict__ mvp,
    const unsigned long long* __restrict__ MB,
    const uint8_t* __restrict__ Kbf, const uint8_t* __restrict__ Vtbf,
    float* __restrict__ out)
{
    extern __shared__ __align__(16) char lds[];
    const int tid  = threadIdx.x;
    const int lane = tid & 63;
    const int w    = tid >> 6;
    const int h    = lane >> 5;          // half (contraction sub-k)
    const int l31  = lane & 31;
    const int swzK7  = (lane & 7)  << 4; // K-image read swizzle (matches (key&7)<<4)
    const int swzV15 = (lane & 15) << 4; // V-image read swizzle (matches (d&15)<<4)

    // XCD-chunked: 8 XCDs x 64 blocks (4 heads); big/small interleaved q-tiles (LPT-ish)
    const int bid = blockIdx.x;
    const int r   = bid >> 3;
    const int bh  = (bid & 7) * 4 + (r >> 4);
    const int tt  = r & 15;
    const int qb  = (tt & 1) ? (tt >> 1) : (15 - (tt >> 1));
    const int b   = bh & (NBATCH - 1);
    const int q0  = qb * 128;
    const int nt  = qb + 1;
    const int wq  = q0 + w * 32 + l31;

    const size_t ho = (size_t)bh * S_LEN * HDIM;
    const uint8_t* kimg = Kbf  + (size_t)bh * 16 * 16384;
    const uint8_t* vimg = Vtbf + (size_t)bh * 16 * 16384;

    auto STAGE = [&](int ti, int bufb) {
        const uint8_t* gk = kimg + (size_t)ti * 16384 + tid * 16;
        const uint8_t* gv = vimg + (size_t)ti * 16384 + tid * 16;
        char* dk = &lds[bufb + tid * 16];
        char* dv = &lds[bufb + 16384 + tid * 16];
        #pragma unroll
        for (int c = 0; c < 4; ++c) {
            load_lds16(gk + c * 4096, dk + c * 4096);
            load_lds16(gv + c * 4096, dv + c * 4096);
        }
    };

    // ---- Q fragments (B-operand of swapped QK^T): col q = lane&31, k-elem d = 16c+8h+j
    bf16x8 qf[4];
    {
        const float* qrow = Q + ho + (size_t)wq * HDIM;
        #pragma unroll
        for (int c = 0; c < 4; ++c) {
            const int d0 = 16 * c + 8 * h;
            float4 f0 = *(const float4*)(qrow + d0);
            float4 f1 = *(const float4*)(qrow + d0 + 4);
            int4 qi;
            qi.x = cvt_pk_bf16(f0.x * QK_SCALE, f0.y * QK_SCALE);
            qi.y = cvt_pk_bf16(f0.z * QK_SCALE, f0.w * QK_SCALE);
            qi.z = cvt_pk_bf16(f1.x * QK_SCALE, f1.y * QK_SCALE);
            qi.w = cvt_pk_bf16(f1.z * QK_SCALE, f1.w * QK_SCALE);
            qf[c] = *(bf16x8*)&qi;
        }
    }

    f32x16 acc[2];
    #pragma unroll
    for (int i = 0; i < 16; ++i) { acc[0][i] = 0.f; acc[1][i] = 0.f; }
    float m_r = 0.f;   // floor at 0: fully-killed rows stay exact-zero
    float l_r = 0.f;

    STAGE(0, 0);
    __syncthreads();

    for (int it = 0; it < nt; ++it) {
        const int kb = (it & 1) << 15;
        if (it + 1 < nt) STAGE(it + 1, kb ^ 32768);

        // ---- QK^T swapped: S^T[key][q] = mfma(A=K, B=Q); C: col=q=lane&31, row=key
        f32x16 s[4];
        #pragma unroll
        for (int g = 0; g < 4; ++g)
            #pragma unroll
            for (int i = 0; i < 16; ++i) s[g][i] = 0.f;
        __builtin_amdgcn_s_setprio(1);
        #pragma unroll
        for (int g = 0; g < 4; ++g) {
            const int rowb = kb + (l31 + 32 * (g & 1)) * 256 + (g >> 1) * 128;
            #pragma unroll
            for (int c = 0; c < 4; ++c) {
                bf16x8 kf = *(const bf16x8*)&lds[rowb + ((32 * c + 16 * h) ^ swzK7)];
                s[g] = __builtin_amdgcn_mfma_f32_32x32x16_bf16(kf, qf[c], s[g], 0, 0, 0);
            }
        }
        __builtin_amdgcn_s_setprio(0);

        // ---- kill mask: key-padding word | causal word (diag iter only)
        unsigned long long mb0 = MB[(b << 5) + 2 * it];
        unsigned long long mb1 = MB[(b << 5) + 2 * it + 1];
        if (it == nt - 1) {
            const int wr = wq & 127;
            mb0 |= (wr >= 63) ? 0ull : (~0ull << (wr + 1));
            const int r1 = wr - 64;
            mb1 |= (r1 >= 63) ? 0ull : ((r1 < 0) ? ~0ull : (~0ull << (r1 + 1)));
        }
        const unsigned long long w0 = mb0 >> (4 * h), w1 = mb1 >> (4 * h);
        const unsigned int wgs[4] = { (unsigned int)w0, (unsigned int)(w0 >> 32),
                                      (unsigned int)w1, (unsigned int)(w1 >> 32) };

        float mloc = NEG_BIG;
        #pragma unroll
        for (int g = 0; g < 4; ++g) {
            const unsigned int wg = wgs[g];
            #pragma unroll
            for (int i = 0; i < 16; ++i) {
                const int c = (i & 3) + 8 * (i >> 2);
                float v = ((wg >> c) & 1u) ? NEG_BIG : s[g][i];
                s[g][i] = v;
                mloc = fmaxf(mloc, v);
            }
        }
        mloc = fmaxf(mloc, __shfl_xor(mloc, 32, 64));

        // ---- defer-max (T13): rescale only on material max growth (rare)
        if (!__all(mloc - m_r <= DEFER_THR)) {
            const float newm = fmaxf(m_r, mloc);
            const float sc = exp2f(m_r - newm);
            l_r *= sc; m_r = newm;
            #pragma unroll
            for (int i = 0; i < 16; ++i) {
                const float sci = __shfl(sc, (i & 3) + 8 * (i >> 2) + 4 * h, 64);
                acc[0][i] *= sci; acc[1][i] *= sci;
            }
        }

        // ---- exp + row-sum + in-register P pack (cvt_pk + permlane32_swap)
        bf16x8 pf[8];
        float lsg[4];
        #pragma unroll
        for (int g = 0; g < 4; ++g) {
            float p[16];
            #pragma unroll
            for (int i = 0; i < 16; ++i) p[i] = exp2f(s[g][i] - m_r);
            float a0 = (p[0] + p[1]) + (p[2] + p[3]);
            float a1 = (p[4] + p[5]) + (p[6] + p[7]);
            float a2 = (p[8] + p[9]) + (p[10] + p[11]);
            float a3 = (p[12] + p[13]) + (p[14] + p[15]);
            lsg[g] = (a0 + a1) + (a2 + a3);
            unsigned int Ap[4], Bp[4];
            #pragma unroll
            for (int s4 = 0; s4 < 4; ++s4) {
                Ap[s4] = cvt_pk_bf16(p[4*s4+0], p[4*s4+1]);  // local keys (8s4+4h, +1)
                Bp[s4] = cvt_pk_bf16(p[4*s4+2], p[4*s4+3]);  // local keys (8s4+4h+2, +3)
            }
            // k-chunk u=0 (local keys 0..15): (R0,R2)=swap(A0,A1), (R1,R3)=swap(B0,B1)
            {
                unsigned int r0 = Ap[0], r2 = Ap[1]; permswap(r0, r2);
                unsigned int r1 = Bp[0], r3 = Bp[1]; permswap(r1, r3);
                int4 f = { (int)r0, (int)r1, (int)r2, (int)r3 };
                pf[2*g] = *(bf16x8*)&f;
            }
            // k-chunk u=1 (local keys 16..31)
            {
                unsigned int r0 = Ap[2], r2 = Ap[3]; permswap(r0, r2);
                unsigned int r1 = Bp[2], r3 = Bp[3]; permswap(r1, r3);
                int4 f = { (int)r0, (int)r1, (int)r2, (int)r3 };
                pf[2*g+1] = *(bf16x8*)&f;
            }
        }
        float ls = (lsg[0] + lsg[1]) + (lsg[2] + lsg[3]);
        ls += __shfl_xor(ls, 32, 64);
        l_r += ls;

        // ---- PV: O[32q][64d] += P[32q][128k] V[128k][64d]
        __builtin_amdgcn_s_setprio(1);
        #pragma unroll
        for (int kp = 0; kp < 8; ++kp) {
            #pragma unroll
            for (int nd = 0; nd < 2; ++nd) {
                bf16x8 vf = *(const bf16x8*)&lds[kb + 16384 + (32 * nd + l31) * 256
                                                + ((32 * kp + 16 * h) ^ swzV15)];
                acc[nd] = __builtin_amdgcn_mfma_f32_32x32x16_bf16(pf[kp], vf, acc[nd], 0, 0, 0);
            }
        }
        __builtin_amdgcn_s_setprio(0);

        __syncthreads();
    }

    // ---- epilogue: normalize; dead rows (l==0) -> full mean(V)
    float lrv[16];
    bool deadl = false;
    #pragma unroll
    for (int i = 0; i < 16; ++i) {
        lrv[i] = __shfl(l_r, (i & 3) + 8 * (i >> 2) + 4 * h, 64);
        deadl |= (lrv[i] == 0.f);
    }
    float mv0 = 0.f, mv1 = 0.f;
    if (__any(deadl)) {
        #pragma unroll
        for (int ttn = 0; ttn < 16; ++ttn) {
            mv0 += bf2f(mvp[(bh * 16 + ttn) * 64 + l31]);
            mv1 += bf2f(mvp[(bh * 16 + ttn) * 64 + l31 + 32]);
        }
    }
    #pragma unroll
    for (int i = 0; i < 16; ++i) {
        const int qrow = q0 + w * 32 + (i & 3) + 8 * (i >> 2) + 4 * h;
        float* o = out + ho + (size_t)qrow * HDIM + l31;
        if (lrv[i] == 0.f) {
            o[0]  = mv0;
            o[32] = mv1;
        } else {
            const float inv = 1.0f / lrv[i];
            o[0]  = acc[0][i] * inv;
            o[32] = acc[1][i] * inv;
        }
    }
}

extern "C" void kernel_launch(void* const* d_in, const int* in_sizes, int n_in,
                              void* d_out, int out_size, void* d_ws, size_t ws_size,
                              hipStream_t stream)
{
    const float* Q     = (const float*)d_in[0];
    const float* K     = (const float*)d_in[1];
    const float* V     = (const float*)d_in[2];
    const int*   masks = (const int*)d_in[3];
    float* out = (float*)d_out;

    char* ws = (char*)d_ws;
    unsigned long long* MB = (unsigned long long*)(ws + WS_MB);
    unsigned short* mvp    = (unsigned short*)(ws + WS_MVP);
    uint8_t* Kbf  = (uint8_t*)(ws + WS_KBF);
    uint8_t* Vtbf = (uint8_t*)(ws + WS_VTBF);

    hipFuncSetAttribute(reinterpret_cast<const void*>(&attn_fwd),
                        hipFuncAttributeMaxDynamicSharedMemorySize, 65536);

    cvt_kernel<<<dim3(512), dim3(256), 0, stream>>>(K, V, masks, Kbf, Vtbf, mvp, MB);
    attn_fwd<<<dim3(512), dim3(256), 65536, stream>>>(Q, mvp, MB, Kbf, Vtbf, out);
}